// Round 1
// baseline (1725.286 us; speedup 1.0000x reference)
//
#include <hip/hip_runtime.h>

#define EPSV 1e-5f

typedef __attribute__((ext_vector_type(8))) short bf16x8;
typedef __attribute__((ext_vector_type(4))) float f32x4;

__device__ inline unsigned short f2bf(float f){
    unsigned u = __float_as_uint(f);
    u += 0x7fffu + ((u >> 16) & 1u);
    return (unsigned short)(u >> 16);
}

// ---------------- setup kernels ----------------

__global__ void k_init(int* deg, int* cursor, int N, int* src_s, int Emax,
                       float* stats, int statsN, float* pool, int poolN, float* nmax){
    int total = N * 64;
    for (int i = blockIdx.x*blockDim.x + threadIdx.x; i < total; i += gridDim.x*blockDim.x){
        nmax[i] = 0.f;
        if (i < N){ deg[i] = 0; cursor[i] = 0; }
        if (i < Emax) src_s[i] = -1;
        if (i < statsN) stats[i] = 0.f;
        if (i < poolN)  pool[i]  = 0.f;
    }
}

__global__ void k_hist(const int* dst, int E, int* deg){
    for (int e = blockIdx.x*blockDim.x + threadIdx.x; e < E; e += gridDim.x*blockDim.x)
        atomicAdd(&deg[dst[e]], 1);
}

__global__ __launch_bounds__(1024) void k_scan(const int* deg, int N, int* pad_off, int* counters){
    __shared__ int lds[1024];
    int t = threadIdx.x;
    int chunk = (N + 1023) >> 10;
    int s0 = t * chunk, s1 = min(s0 + chunk, N);
    int s = 0;
    for (int i = s0; i < s1; i++) s += ((deg[i] + 15) & ~15);
    lds[t] = s; __syncthreads();
    for (int off = 1; off < 1024; off <<= 1){
        int v = (t >= off) ? lds[t - off] : 0;
        __syncthreads();
        lds[t] += v;
        __syncthreads();
    }
    int run = (t == 0) ? 0 : lds[t - 1];
    for (int i = s0; i < s1; i++){ pad_off[i] = run; run += ((deg[i] + 15) & ~15); }
    if (t == 1023){
        counters[0] = lds[1023] >> 4;  // number of 16-edge groups
        counters[1] = lds[1023];       // padded edge count
        pad_off[N] = lds[1023];
    }
}

__global__ void k_grpfill(const int* deg, const int* pad_off, int N, int* grp_node, int* grp_vc){
    for (int n = blockIdx.x*blockDim.x + threadIdx.x; n < N; n += gridDim.x*blockDim.x){
        int dg = deg[n];
        int g0 = pad_off[n] >> 4;
        int ng = (dg + 15) >> 4;
        for (int j = 0; j < ng; j++){
            grp_node[g0 + j] = n;
            grp_vc[g0 + j] = min(dg - j*16, 16);
        }
    }
}

__global__ void k_scatter(const int* src, const int* dst, const float* ea, int E,
                          const int* pad_off, int* cursor, int* src_s, float* ea_s){
    for (int e = blockIdx.x*blockDim.x + threadIdx.x; e < E; e += gridDim.x*blockDim.x){
        int d = dst[e];
        int p = pad_off[d] + atomicAdd(&cursor[d], 1);
        src_s[p] = src[e];
        ea_s[p] = ea[e];
    }
}

__global__ void k_bounds(const int* batch, int N, int B, int* bstart){
    for (int n = blockIdx.x*blockDim.x + threadIdx.x; n < N; n += gridDim.x*blockDim.x){
        if (n == 0){ int b0 = batch[0]; for (int bb = 0; bb <= b0; bb++) bstart[bb] = 0; }
        int b1 = batch[n];
        int b2 = (n + 1 < N) ? batch[n + 1] : B;
        for (int bb = b1 + 1; bb <= b2; bb++) bstart[bb] = n + 1;
    }
}

__global__ void k_w1bf(const float* c1W1, const float* cwW1, unsigned short* w1bf){
    int i = blockIdx.x*blockDim.x + threadIdx.x;
    if (i < 4*4096){
        int l = i >> 12, r = i & 4095;
        float v = (l == 0) ? c1W1[r] : cwW1[(l-1)*4096 + r];
        w1bf[i] = f2bf(v);
    }
}

// ---------------- per-layer kernels ----------------

// P = xc @ Wa ; Q = xc @ (Wb - Wa) + b0   (xc = [pos(3), feat(F)])
__global__ __launch_bounds__(256) void k_nodeproj(const float* __restrict__ pos,
        const float* __restrict__ feat, int F, const float* __restrict__ W,
        int ra, int rb, const float* __restrict__ b0,
        float* __restrict__ P, float* __restrict__ Q, int N){
    __shared__ float sWa[67*64];
    __shared__ float sWd[67*64];
    int D = 3 + F;
    for (int i = threadIdx.x; i < D*64; i += 256){
        int k = i >> 6, c = i & 63;
        float wa = W[(ra + k)*64 + c];
        sWa[i] = wa;
        sWd[i] = W[(rb + k)*64 + c] - wa;
    }
    __syncthreads();
    int lane = threadIdx.x & 63;
    int wid = (blockIdx.x*256 + threadIdx.x) >> 6;
    int nw  = (gridDim.x*256) >> 6;
    float bb = b0[lane];
    for (int n = wid; n < N; n += nw){
        float p = 0.f, q = 0.f;
        for (int k = 0; k < 3; k++){
            float v = pos[n*3 + k];
            p = fmaf(v, sWa[k*64 + lane], p);
            q = fmaf(v, sWd[k*64 + lane], q);
        }
        for (int k = 0; k < F; k++){
            float v = feat[n*F + k];
            p = fmaf(v, sWa[(3+k)*64 + lane], p);
            q = fmaf(v, sWd[(3+k)*64 + lane], q);
        }
        P[(size_t)n*64 + lane] = p;
        Q[(size_t)n*64 + lane] = q + bb;
    }
}

// BN0 stats over all edges (original order): sum/sumsq of relu(P[src]+Q[dst] (+ea*w0))
__global__ __launch_bounds__(256) void k_passA(const float* __restrict__ P, const float* __restrict__ Q,
        const int* __restrict__ src, const int* __restrict__ dst,
        const float* __restrict__ ea, const float* __restrict__ w0e, int E,
        float* sum0, float* sq0){
    int lane = threadIdx.x & 63, w = threadIdx.x >> 6;
    int wid = (blockIdx.x*256 + threadIdx.x) >> 6;
    int nw  = (gridDim.x*256) >> 6;
    float w0 = w0e ? w0e[lane] : 0.f;
    float s1 = 0.f, s2 = 0.f;
    for (int e = wid; e < E; e += nw){
        int s = src[e], d = dst[e];
        float v = P[(size_t)s*64 + lane] + Q[(size_t)d*64 + lane];
        if (ea) v = fmaf(ea[e], w0, v);
        float h = fmaxf(v, 0.f);
        s1 += h; s2 = fmaf(h, h, s2);
    }
    __shared__ float red[256];
    red[threadIdx.x] = s1; __syncthreads();
    if (w == 0) atomicAdd(&sum0[lane], red[lane] + red[64+lane] + red[128+lane] + red[192+lane]);
    __syncthreads();
    red[threadIdx.x] = s2; __syncthreads();
    if (w == 0) atomicAdd(&sq0[lane], red[lane] + red[64+lane] + red[128+lane] + red[192+lane]);
}

__global__ void k_bnfin(const float* sum, const float* sq, float invE,
                        const float* g, const float* be, float* a, float* c){
    int t = threadIdx.x;
    if (t < 64){
        float m = sum[t] * invE;
        float v = fmaxf(sq[t]*invE - m*m, 0.f);
        float r = rsqrtf(v + EPSV);
        float av = g[t] * r;
        a[t] = av;
        c[t] = be[t] - m * av;
    }
}

// pass B: per 16-edge (single-dst) group: y = BN0(relu(pre)) -> h1 = relu(y@W1+b1) via MFMA,
// scatter-max h1 into nmax (uint-punned, h1>=0), accumulate BN1 stats.
__global__ __launch_bounds__(256) void k_passB(const float* __restrict__ P, const float* __restrict__ Q,
        const int* __restrict__ src_s, const float* __restrict__ ea_s, const float* __restrict__ w0e,
        const int* __restrict__ grp_node, const int* __restrict__ grp_vc, const int* __restrict__ counters,
        const float* __restrict__ a0, const float* __restrict__ c0,
        const unsigned short* __restrict__ w1bf, const float* __restrict__ b1,
        float* nmax, float* sum1, float* sq1){
    int lane = threadIdx.x & 63;
    int lo = lane & 15, hi = lane >> 4;
    int wid = (blockIdx.x*256 + threadIdx.x) >> 6;
    int nw  = (gridDim.x*256) >> 6;

    // B fragments of W1 (bf16): B[k][n], n = 16*nt + lo, k = ks*32 + hi*8 + j
    bf16x8 bfr[2][4];
#pragma unroll
    for (int ks = 0; ks < 2; ks++)
#pragma unroll
        for (int nt = 0; nt < 4; nt++)
#pragma unroll
            for (int j = 0; j < 8; j++){
                int k = ks*32 + hi*8 + j;
                bfr[ks][nt][j] = (short)w1bf[k*64 + nt*16 + lo];
            }
    float b1v[4];
#pragma unroll
    for (int nt = 0; nt < 4; nt++) b1v[nt] = b1[nt*16 + lo];
    float a0v[16], c0v[16], w0v[16];
#pragma unroll
    for (int ks = 0; ks < 2; ks++)
#pragma unroll
        for (int j = 0; j < 8; j++){
            int k = ks*32 + hi*8 + j;
            a0v[ks*8+j] = a0[k];
            c0v[ks*8+j] = c0[k];
            w0v[ks*8+j] = w0e ? w0e[k] : 0.f;
        }

    float st1[4] = {0.f,0.f,0.f,0.f}, st2[4] = {0.f,0.f,0.f,0.f};
    int NG = counters[0];
    for (int g = wid; g < NG; g += nw){
        int n = grp_node[g];
        int vc = grp_vc[g];
        int e = g*16 + lo;
        int sv = src_s[e];
        float eav = 0.f;
        if (w0e && sv >= 0) eav = ea_s[e];
        int s = (sv < 0) ? 0 : sv;
        const f32x4* P4 = (const f32x4*)(P + (size_t)s*64);
        const f32x4* Q4 = (const f32x4*)(Q + (size_t)n*64);
        f32x4 p0 = P4[hi*2+0], p1 = P4[hi*2+1], p2 = P4[hi*2+8], p3 = P4[hi*2+9];
        f32x4 q0 = Q4[hi*2+0], q1 = Q4[hi*2+1], q2 = Q4[hi*2+8], q3 = Q4[hi*2+9];
        bf16x8 af0, af1;
#pragma unroll
        for (int j = 0; j < 8; j++){
            float pv = (j < 4) ? p0[j] : p1[j-4];
            float qv = (j < 4) ? q0[j] : q1[j-4];
            float pre = fmaf(eav, w0v[j], pv + qv);
            float h = fmaxf(pre, 0.f);
            float y = fmaf(a0v[j], h, c0v[j]);
            af0[j] = (short)f2bf(y);
        }
#pragma unroll
        for (int j = 0; j < 8; j++){
            float pv = (j < 4) ? p2[j] : p3[j-4];
            float qv = (j < 4) ? q2[j] : q3[j-4];
            float pre = fmaf(eav, w0v[8+j], pv + qv);
            float h = fmaxf(pre, 0.f);
            float y = fmaf(a0v[8+j], h, c0v[8+j]);
            af1[j] = (short)f2bf(y);
        }
        f32x4 acc[4];
#pragma unroll
        for (int nt = 0; nt < 4; nt++){
            acc[nt] = (f32x4){0.f, 0.f, 0.f, 0.f};
            acc[nt] = __builtin_amdgcn_mfma_f32_16x16x32_bf16(af0, bfr[0][nt], acc[nt], 0, 0, 0);
            acc[nt] = __builtin_amdgcn_mfma_f32_16x16x32_bf16(af1, bfr[1][nt], acc[nt], 0, 0, 0);
        }
#pragma unroll
        for (int nt = 0; nt < 4; nt++){
            float m = 0.f;
#pragma unroll
            for (int r = 0; r < 4; r++){
                bool valid = (hi*4 + r) < vc;     // D row = edge-in-group = 4*hi + r
                float h = valid ? fmaxf(acc[nt][r] + b1v[nt], 0.f) : 0.f;
                st1[nt] += h;
                st2[nt] = fmaf(h, h, st2[nt]);
                m = fmaxf(m, h);
            }
            m = fmaxf(m, __shfl_xor(m, 16));
            m = fmaxf(m, __shfl_xor(m, 32));
            if (lane < 16)
                atomicMax((unsigned int*)&nmax[(size_t)n*64 + nt*16 + lane], __float_as_uint(m));
        }
    }
#pragma unroll
    for (int nt = 0; nt < 4; nt++){
        st1[nt] += __shfl_xor(st1[nt], 16); st1[nt] += __shfl_xor(st1[nt], 32);
        st2[nt] += __shfl_xor(st2[nt], 16); st2[nt] += __shfl_xor(st2[nt], 32);
    }
    if (lane < 16){
#pragma unroll
        for (int nt = 0; nt < 4; nt++){
            atomicAdd(&sum1[nt*16 + lane], st1[nt]);
            atomicAdd(&sq1[nt*16 + lane], st2[nt]);
        }
    }
}

// finalize: h = indeg>0 ? relu(a1*max + c1) : 0 ; reset nmax; fused mean-pool accumulation
__global__ __launch_bounds__(256) void k_fin(float* nmax, const int* __restrict__ deg,
        const float* __restrict__ a1, const float* __restrict__ c1,
        const int* __restrict__ batch, float* __restrict__ hout, float* pooll, int N, int B){
    int lane = threadIdx.x & 63;
    int wid = (blockIdx.x*256 + threadIdx.x) >> 6;
    int nw  = (gridDim.x*256) >> 6;
    int chunk = (N + nw - 1) / nw;
    int n0 = wid * chunk, n1 = min(n0 + chunk, N);
    float av = a1[lane], cv = c1[lane];
    int rep = wid & 7;
    float run = 0.f; int curb = -1;
    for (int n = n0; n < n1; n++){
        size_t idx = (size_t)n*64 + lane;
        float mv = nmax[idx];
        nmax[idx] = 0.f;
        float val = (deg[n] > 0) ? fmaxf(fmaf(av, mv, cv), 0.f) : 0.f;
        hout[idx] = val;
        int b = batch[n];
        if (b != curb){
            if (curb >= 0) atomicAdd(&pooll[(rep*B + curb)*64 + lane], run);
            run = 0.f; curb = b;
        }
        run += val;
    }
    if (curb >= 0) atomicAdd(&pooll[(rep*B + curb)*64 + lane], run);
}

// head: jump-cat pooled means -> lin1 -> relu -> lin2 -> log_softmax
__global__ __launch_bounds__(512) void k_head(const float* __restrict__ pool, const int* __restrict__ bstart,
        const float* __restrict__ l1W, const float* __restrict__ l1b,
        const float* __restrict__ l2W, const float* __restrict__ l2b,
        float* __restrict__ out, int B, int NCLS){
    __shared__ float js[8*256];
    __shared__ float z1[8*64];
    __shared__ float zs[8*40];
    int t = threadIdx.x;
    for (int i = t; i < B*256; i += 512){
        int b = i >> 8, k = i & 255;
        int l = k >> 6, c = k & 63;
        float s = 0.f;
        for (int r = 0; r < 8; r++) s += pool[((l*8 + r)*B + b)*64 + c];
        float cnt = (float)(bstart[b+1] - bstart[b]);
        js[b*256 + k] = s / fmaxf(cnt, 1.f);
    }
    __syncthreads();
    for (int i = t; i < B*64; i += 512){
        int b = i >> 6, c = i & 63;
        float acc = l1b[c];
        for (int k = 0; k < 256; k++) acc = fmaf(js[b*256 + k], l1W[k*64 + c], acc);
        z1[i] = fmaxf(acc, 0.f);
    }
    __syncthreads();
    for (int i = t; i < B*NCLS; i += 512){
        int b = i / NCLS, c = i - b*NCLS;
        float acc = l2b[c];
        for (int k = 0; k < 64; k++) acc = fmaf(z1[b*64 + k], l2W[k*NCLS + c], acc);
        zs[b*NCLS + c] = acc;
    }
    __syncthreads();
    if (t < B){
        float m = -1e30f;
        for (int c = 0; c < NCLS; c++) m = fmaxf(m, zs[t*NCLS + c]);
        float se = 0.f;
        for (int c = 0; c < NCLS; c++) se += expf(zs[t*NCLS + c] - m);
        float lse = m + logf(se);
        for (int c = 0; c < NCLS; c++) out[t*NCLS + c] = zs[t*NCLS + c] - lse;
    }
}

// ---------------- host ----------------

extern "C" void kernel_launch(void* const* d_in, const int* in_sizes, int n_in,
                              void* d_out, int out_size, void* d_ws, size_t ws_size,
                              hipStream_t stream){
    const float* x      = (const float*)d_in[0];
    const float* pos    = (const float*)d_in[1];
    const float* eattr  = (const float*)d_in[2];
    const int*   eidx   = (const int*)d_in[3];
    const int*   batch  = (const int*)d_in[4];
    const float* c1_W0  = (const float*)d_in[5];
    const float* c1_b0  = (const float*)d_in[6];
    const float* c1_g0  = (const float*)d_in[7];
    const float* c1_be0 = (const float*)d_in[8];
    const float* c1_W1  = (const float*)d_in[9];
    const float* c1_b1  = (const float*)d_in[10];
    const float* c1_g1  = (const float*)d_in[11];
    const float* c1_be1 = (const float*)d_in[12];
    const float* cw_W0  = (const float*)d_in[13];
    const float* cw_b0  = (const float*)d_in[14];
    const float* cw_g0  = (const float*)d_in[15];
    const float* cw_be0 = (const float*)d_in[16];
    const float* cw_W1  = (const float*)d_in[17];
    const float* cw_b1  = (const float*)d_in[18];
    const float* cw_g1  = (const float*)d_in[19];
    const float* cw_be1 = (const float*)d_in[20];
    const float* lin1_W = (const float*)d_in[21];
    const float* lin1_b = (const float*)d_in[22];
    const float* lin2_W = (const float*)d_in[23];
    const float* lin2_b = (const float*)d_in[24];
    float* out = (float*)d_out;

    int N = in_sizes[0] / 3;
    int E = in_sizes[2];
    int NCLS = in_sizes[24];
    int B = out_size / NCLS;
    const int* src = eidx;
    const int* dst = eidx + E;

    // workspace carve-up
    char* w = (char*)d_ws;
    auto alloc = [&](size_t bytes) -> char* {
        char* p = w;
        w += (bytes + 255) & ~(size_t)255;
        return p;
    };
    int Emax = E + 16*N;
    int Gmax = E/16 + N + 2;
    float* P        = (float*)alloc((size_t)N*64*4);
    float* Q        = (float*)alloc((size_t)N*64*4);
    float* hA       = (float*)alloc((size_t)N*64*4);
    float* hB       = (float*)alloc((size_t)N*64*4);
    float* nmax     = (float*)alloc((size_t)N*64*4);
    int*   deg      = (int*)alloc((size_t)N*4);
    int*   pad_off  = (int*)alloc((size_t)(N+1)*4);
    int*   cursor   = (int*)alloc((size_t)N*4);
    int*   src_s    = (int*)alloc((size_t)Emax*4);
    float* ea_s     = (float*)alloc((size_t)Emax*4);
    int*   grp_node = (int*)alloc((size_t)Gmax*4);
    int*   grp_vc   = (int*)alloc((size_t)Gmax*4);
    int*   counters = (int*)alloc(256);
    int*   bstart   = (int*)alloc((size_t)(B+1)*4);
    float* stats    = (float*)alloc(4*256*4);   // per layer: sum0, sq0, sum1, sq1 (64 each)
    float* aff      = (float*)alloc(4*256*4);   // per layer: a0, c0, a1, c1
    unsigned short* w1bf = (unsigned short*)alloc(4*4096*2);
    float* pool     = (float*)alloc((size_t)4*8*B*64*4);

    float invE = 1.f / (float)E;
    int eblocks = (E + 255) / 256;
    int nblocks = (N + 255) / 256;

    k_init<<<2048, 256, 0, stream>>>(deg, cursor, N, src_s, Emax, stats, 4*256, pool, 4*8*B*64, nmax);
    k_hist<<<eblocks, 256, 0, stream>>>(dst, E, deg);
    k_scan<<<1, 1024, 0, stream>>>(deg, N, pad_off, counters);
    k_grpfill<<<nblocks, 256, 0, stream>>>(deg, pad_off, N, grp_node, grp_vc);
    k_scatter<<<eblocks, 256, 0, stream>>>(src, dst, eattr, E, pad_off, cursor, src_s, ea_s);
    k_bounds<<<nblocks, 256, 0, stream>>>(batch, N, B, bstart);
    k_w1bf<<<64, 256, 0, stream>>>(c1_W1, cw_W1, w1bf);

    for (int l = 0; l < 4; l++){
        const float* feat = (l == 0) ? x : ((l == 1) ? hA : ((l == 2) ? hB : hA));
        float* hout = (l & 1) ? hB : hA;
        int F  = (l == 0) ? 3 : 64;
        int ra = (l == 0) ? 1 : 0;
        int rb = (l == 0) ? 7 : 67;
        const float* W0  = (l == 0) ? c1_W0  : cw_W0  + (size_t)(l-1)*134*64;
        const float* b0  = (l == 0) ? c1_b0  : cw_b0  + (l-1)*64;
        const float* g0  = (l == 0) ? c1_g0  : cw_g0  + (l-1)*64;
        const float* be0 = (l == 0) ? c1_be0 : cw_be0 + (l-1)*64;
        const float* b1  = (l == 0) ? c1_b1  : cw_b1  + (l-1)*64;
        const float* g1  = (l == 0) ? c1_g1  : cw_g1  + (l-1)*64;
        const float* be1 = (l == 0) ? c1_be1 : cw_be1 + (l-1)*64;
        const float* w0e = (l == 0) ? c1_W0 : nullptr;   // W0 row 0 = edge_attr weights
        const float* eaA = (l == 0) ? eattr : nullptr;
        float* sum0 = stats + l*256;       float* sq0 = sum0 + 64;
        float* sum1 = sum0 + 128;          float* sq1 = sum0 + 192;
        float* a0 = aff + l*256;           float* c0 = a0 + 64;
        float* a1 = a0 + 128;              float* c1v = a0 + 192;
        const unsigned short* w1l = w1bf + (size_t)l*4096;
        float* pooll = pool + (size_t)l*8*B*64;

        k_nodeproj<<<512, 256, 0, stream>>>(pos, feat, F, W0, ra, rb, b0, P, Q, N);
        k_passA<<<1024, 256, 0, stream>>>(P, Q, src, dst, eaA, w0e, E, sum0, sq0);
        k_bnfin<<<1, 64, 0, stream>>>(sum0, sq0, invE, g0, be0, a0, c0);
        k_passB<<<1024, 256, 0, stream>>>(P, Q, src_s, ea_s, w0e, grp_node, grp_vc, counters,
                                          a0, c0, w1l, b1, nmax, sum1, sq1);
        k_bnfin<<<1, 64, 0, stream>>>(sum1, sq1, invE, g1, be1, a1, c1v);
        k_fin<<<256, 256, 0, stream>>>(nmax, deg, a1, c1v, batch, hout, pooll, N, B);
    }

    k_head<<<1, 512, 0, stream>>>(pool, bstart, lin1_W, lin1_b, lin2_W, lin2_b, out, B, NCLS);
}

// Round 2
// 1098.966 us; speedup vs baseline: 1.5699x; 1.5699x over previous
//
#include <hip/hip_runtime.h>

#define EPSV 1e-5f

typedef __attribute__((ext_vector_type(8))) short bf16x8;
typedef __attribute__((ext_vector_type(8))) unsigned short u16x8;
typedef __attribute__((ext_vector_type(4))) float f32x4;

__device__ inline unsigned short f2bf(float f){
    unsigned u = __float_as_uint(f);
    u += 0x7fffu + ((u >> 16) & 1u);
    return (unsigned short)(u >> 16);
}
__device__ inline float bf2f(unsigned short v){
    return __uint_as_float(((unsigned)v) << 16);
}

// ---------------- setup kernels ----------------

__global__ void k_init(int* deg, int* cursor, int N,
                       float* stats, int statsN, float* pool, int poolN, float* nmax){
    int total = N * 64;
    for (int i = blockIdx.x*blockDim.x + threadIdx.x; i < total; i += gridDim.x*blockDim.x){
        nmax[i] = 0.f;
        if (i < N){ deg[i] = 0; cursor[i] = 0; }
        if (i < statsN) stats[i] = 0.f;
        if (i < poolN)  pool[i]  = 0.f;
    }
}

__global__ void k_hist(const int* dst, int E, int* deg){
    for (int e = blockIdx.x*blockDim.x + threadIdx.x; e < E; e += gridDim.x*blockDim.x)
        atomicAdd(&deg[dst[e]], 1);
}

// prefix sums: estart (edges, unpadded CSR) and gstart (16-edge groups)
__global__ __launch_bounds__(1024) void k_scan(const int* deg, int N,
                                               int* estart, int* gstart, int* counters){
    __shared__ int ldsE[1024];
    __shared__ int ldsG[1024];
    int t = threadIdx.x;
    int chunk = (N + 1023) >> 10;
    int s0 = t * chunk, s1 = min(s0 + chunk, N);
    int se = 0, sg = 0;
    for (int i = s0; i < s1; i++){ int d = deg[i]; se += d; sg += (d + 15) >> 4; }
    ldsE[t] = se; ldsG[t] = sg; __syncthreads();
    for (int off = 1; off < 1024; off <<= 1){
        int ve = (t >= off) ? ldsE[t - off] : 0;
        int vg = (t >= off) ? ldsG[t - off] : 0;
        __syncthreads();
        ldsE[t] += ve; ldsG[t] += vg;
        __syncthreads();
    }
    int re = (t == 0) ? 0 : ldsE[t - 1];
    int rg = (t == 0) ? 0 : ldsG[t - 1];
    for (int i = s0; i < s1; i++){
        estart[i] = re; gstart[i] = rg;
        int d = deg[i];
        re += d; rg += (d + 15) >> 4;
    }
    if (t == 1023){
        counters[0] = ldsG[1023];   // total groups
        estart[N] = ldsE[1023];
        gstart[N] = ldsG[1023];
    }
}

__global__ void k_grpfill(const int* deg, const int* estart, const int* gstart, int N,
                          int* grp_node, int* grp_base, int* grp_vc){
    for (int n = blockIdx.x*blockDim.x + threadIdx.x; n < N; n += gridDim.x*blockDim.x){
        int dg = deg[n];
        int g0 = gstart[n];
        int e0 = estart[n];
        int ng = (dg + 15) >> 4;
        for (int j = 0; j < ng; j++){
            grp_node[g0 + j] = n;
            grp_base[g0 + j] = e0 + j*16;
            grp_vc[g0 + j] = min(dg - j*16, 16);
        }
    }
}

__global__ void k_scatter(const int* src, const int* dst, const float* ea, int E,
                          const int* estart, int* cursor, int* src_c, float* ea_c){
    for (int e = blockIdx.x*blockDim.x + threadIdx.x; e < E; e += gridDim.x*blockDim.x){
        int d = dst[e];
        int p = estart[d] + atomicAdd(&cursor[d], 1);
        src_c[p] = src[e];
        ea_c[p] = ea[e];
    }
}

__global__ void k_bounds(const int* batch, int N, int B, int* bstart){
    for (int n = blockIdx.x*blockDim.x + threadIdx.x; n < N; n += gridDim.x*blockDim.x){
        if (n == 0){ int b0 = batch[0]; for (int bb = 0; bb <= b0; bb++) bstart[bb] = 0; }
        int b1 = batch[n];
        int b2 = (n + 1 < N) ? batch[n + 1] : B;
        for (int bb = b1 + 1; bb <= b2; bb++) bstart[bb] = n + 1;
    }
}

__global__ void k_w1bf(const float* c1W1, const float* cwW1, unsigned short* w1bf){
    int i = blockIdx.x*blockDim.x + threadIdx.x;
    if (i < 4*4096){
        int l = i >> 12, r = i & 4095;
        float v = (l == 0) ? c1W1[r] : cwW1[(l-1)*4096 + r];
        w1bf[i] = f2bf(v);
    }
}

// ---------------- per-layer kernels ----------------

// P = xc @ Wa ; Q = xc @ (Wb - Wa) + b0   (xc = [pos(3), feat(F)])
__global__ __launch_bounds__(256) void k_nodeproj(const float* __restrict__ pos,
        const float* __restrict__ feat, int F, const float* __restrict__ W,
        int ra, int rb, const float* __restrict__ b0,
        float* __restrict__ P, float* __restrict__ Q, int N){
    __shared__ float sWa[67*64];
    __shared__ float sWd[67*64];
    int D = 3 + F;
    for (int i = threadIdx.x; i < D*64; i += 256){
        int k = i >> 6, c = i & 63;
        float wa = W[(ra + k)*64 + c];
        sWa[i] = wa;
        sWd[i] = W[(rb + k)*64 + c] - wa;
    }
    __syncthreads();
    int lane = threadIdx.x & 63;
    int wid = (blockIdx.x*256 + threadIdx.x) >> 6;
    int nw  = (gridDim.x*256) >> 6;
    float bb = b0[lane];
    for (int n = wid; n < N; n += nw){
        float p = 0.f, q = 0.f;
        for (int k = 0; k < 3; k++){
            float v = pos[n*3 + k];
            p = fmaf(v, sWa[k*64 + lane], p);
            q = fmaf(v, sWd[k*64 + lane], q);
        }
        for (int k = 0; k < F; k++){
            float v = feat[n*F + k];
            p = fmaf(v, sWa[(3+k)*64 + lane], p);
            q = fmaf(v, sWd[(3+k)*64 + lane], q);
        }
        P[(size_t)n*64 + lane] = p;
        Q[(size_t)n*64 + lane] = q + bb;
    }
}

// stats pass over sorted 16-edge groups: h = relu(P[src]+Q[dst](+ea*w0)),
// accumulate BN0 sum/sumsq, optionally store h as bf16 (compact layout).
// lane = (lo=edge-in-group, hi=channel-quarter); lane covers ch {hi*8+j, 32+hi*8+j}.
__global__ __launch_bounds__(256) void k_statsA(const float* __restrict__ P, const float* __restrict__ Q,
        const int* __restrict__ src_c, const float* __restrict__ ea_c, const float* __restrict__ w0e,
        const int* __restrict__ grp_node, const int* __restrict__ grp_base, const int* __restrict__ grp_vc,
        const int* __restrict__ counters, unsigned short* __restrict__ h0,
        float* sum0, float* sq0){
    int lane = threadIdx.x & 63;
    int lo = lane & 15, hi = lane >> 4;
    int wid = (blockIdx.x*256 + threadIdx.x) >> 6;
    int nw  = (gridDim.x*256) >> 6;
    float w0v[16];
#pragma unroll
    for (int j = 0; j < 8; j++){
        w0v[j]   = w0e ? w0e[hi*8 + j]      : 0.f;
        w0v[8+j] = w0e ? w0e[32 + hi*8 + j] : 0.f;
    }
    float st1[16], st2[16];
#pragma unroll
    for (int j = 0; j < 16; j++){ st1[j] = 0.f; st2[j] = 0.f; }

    int NG = counters[0];
    for (int g = wid; g < NG; g += nw){
        int n = grp_node[g], base = grp_base[g], vc = grp_vc[g];
        bool val = lo < vc;
        int e = base + (val ? lo : 0);
        int s = src_c[e];
        float eav = (w0e && val) ? ea_c[e] : 0.f;
        const f32x4* P4 = (const f32x4*)(P + (size_t)s*64);
        const f32x4* Q4 = (const f32x4*)(Q + (size_t)n*64);
        f32x4 p0 = P4[2*hi], p1 = P4[2*hi+1], p2 = P4[2*hi+8], p3 = P4[2*hi+9];
        f32x4 q0 = Q4[2*hi], q1 = Q4[2*hi+1], q2 = Q4[2*hi+8], q3 = Q4[2*hi+9];
        u16x8 ha, hb;
#pragma unroll
        for (int j = 0; j < 8; j++){
            float pv = (j < 4) ? p0[j] : p1[j-4];
            float qv = (j < 4) ? q0[j] : q1[j-4];
            float h = fmaxf(fmaf(eav, w0v[j], pv + qv), 0.f);
            if (!val) h = 0.f;
            st1[j] += h; st2[j] = fmaf(h, h, st2[j]);
            ha[j] = f2bf(h);
        }
#pragma unroll
        for (int j = 0; j < 8; j++){
            float pv = (j < 4) ? p2[j] : p3[j-4];
            float qv = (j < 4) ? q2[j] : q3[j-4];
            float h = fmaxf(fmaf(eav, w0v[8+j], pv + qv), 0.f);
            if (!val) h = 0.f;
            st1[8+j] += h; st2[8+j] = fmaf(h, h, st2[8+j]);
            hb[j] = f2bf(h);
        }
        if (h0 && val){
            *(u16x8*)(h0 + (size_t)(base + lo)*64 + hi*8) = ha;
            *(u16x8*)(h0 + (size_t)(base + lo)*64 + 32 + hi*8) = hb;
        }
    }
    // reduce across the 16 lo-lanes (xor 1,2,4,8), then block LDS reduce, then atomics
#pragma unroll
    for (int m = 1; m < 16; m <<= 1){
#pragma unroll
        for (int j = 0; j < 16; j++){
            st1[j] += __shfl_xor(st1[j], m);
            st2[j] += __shfl_xor(st2[j], m);
        }
    }
    __shared__ float red[4*128];
    int w = threadIdx.x >> 6;
    if (lo == 0){
#pragma unroll
        for (int j = 0; j < 8; j++){
            red[w*128 + hi*8 + j]        = st1[j];
            red[w*128 + 32 + hi*8 + j]   = st1[8+j];
            red[w*128 + 64 + hi*8 + j]   = st2[j];
            red[w*128 + 96 + hi*8 + j]   = st2[8+j];
        }
    }
    __syncthreads();
    int t = threadIdx.x;
    if (t < 128){
        float v = red[t] + red[128 + t] + red[256 + t] + red[384 + t];
        if (t < 64) atomicAdd(&sum0[t], v);
        else        atomicAdd(&sq0[t - 64], v);
    }
}

__global__ void k_bnfin(const float* sum, const float* sq, float invE,
                        const float* g, const float* be, float* a, float* c){
    int t = threadIdx.x;
    if (t < 64){
        float m = sum[t] * invE;
        float v = fmaxf(sq[t]*invE - m*m, 0.f);
        float r = rsqrtf(v + EPSV);
        float av = g[t] * r;
        a[t] = av;
        c[t] = be[t] - m * av;
    }
}

// pass B: per 16-edge (single-dst) group: y = a0*h + c0 (h from h0 or recomputed),
// h1 = relu(y@W1 + b1) via MFMA, scatter-max into nmax, accumulate BN1 stats.
template<bool REC>
__global__ __launch_bounds__(256) void k_passB2(const unsigned short* __restrict__ h0,
        const float* __restrict__ P, const float* __restrict__ Q,
        const int* __restrict__ src_c, const float* __restrict__ ea_c, const float* __restrict__ w0e,
        const int* __restrict__ grp_node, const int* __restrict__ grp_base, const int* __restrict__ grp_vc,
        const int* __restrict__ counters,
        const float* __restrict__ a0, const float* __restrict__ c0,
        const unsigned short* __restrict__ w1bf, const float* __restrict__ b1,
        float* nmax, float* sum1, float* sq1){
    int lane = threadIdx.x & 63;
    int lo = lane & 15, hi = lane >> 4;
    int wid = (blockIdx.x*256 + threadIdx.x) >> 6;
    int nw  = (gridDim.x*256) >> 6;

    // B fragments of W1 (bf16): B[k][n], n = 16*nt + lo, k = ks*32 + hi*8 + j
    bf16x8 bfr[2][4];
#pragma unroll
    for (int ks = 0; ks < 2; ks++)
#pragma unroll
        for (int nt = 0; nt < 4; nt++)
#pragma unroll
            for (int j = 0; j < 8; j++){
                int k = ks*32 + hi*8 + j;
                bfr[ks][nt][j] = (short)w1bf[k*64 + nt*16 + lo];
            }
    float b1v[4];
#pragma unroll
    for (int nt = 0; nt < 4; nt++) b1v[nt] = b1[nt*16 + lo];
    float a0v[16], c0v[16], w0v[16];
#pragma unroll
    for (int j = 0; j < 8; j++){
        a0v[j]   = a0[hi*8 + j];      a0v[8+j] = a0[32 + hi*8 + j];
        c0v[j]   = c0[hi*8 + j];      c0v[8+j] = c0[32 + hi*8 + j];
        w0v[j]   = w0e ? w0e[hi*8 + j]      : 0.f;
        w0v[8+j] = w0e ? w0e[32 + hi*8 + j] : 0.f;
    }

    float st1[4] = {0.f,0.f,0.f,0.f}, st2[4] = {0.f,0.f,0.f,0.f};
    int NG = counters[0];
    for (int g = wid; g < NG; g += nw){
        int n = grp_node[g], base = grp_base[g], vc = grp_vc[g];
        bf16x8 af0, af1;
        if (REC){
            bool val = lo < vc;
            int e = base + (val ? lo : 0);
            int s = src_c[e];
            float eav = (w0e && val) ? ea_c[e] : 0.f;
            const f32x4* P4 = (const f32x4*)(P + (size_t)s*64);
            const f32x4* Q4 = (const f32x4*)(Q + (size_t)n*64);
            f32x4 p0 = P4[2*hi], p1 = P4[2*hi+1], p2 = P4[2*hi+8], p3 = P4[2*hi+9];
            f32x4 q0 = Q4[2*hi], q1 = Q4[2*hi+1], q2 = Q4[2*hi+8], q3 = Q4[2*hi+9];
#pragma unroll
            for (int j = 0; j < 8; j++){
                float pv = (j < 4) ? p0[j] : p1[j-4];
                float qv = (j < 4) ? q0[j] : q1[j-4];
                float h = fmaxf(fmaf(eav, w0v[j], pv + qv), 0.f);
                af0[j] = (short)f2bf(fmaf(a0v[j], h, c0v[j]));
            }
#pragma unroll
            for (int j = 0; j < 8; j++){
                float pv = (j < 4) ? p2[j] : p3[j-4];
                float qv = (j < 4) ? q2[j] : q3[j-4];
                float h = fmaxf(fmaf(eav, w0v[8+j], pv + qv), 0.f);
                af1[j] = (short)f2bf(fmaf(a0v[8+j], h, c0v[8+j]));
            }
        } else {
            u16x8 ha = *(const u16x8*)(h0 + (size_t)(base + lo)*64 + hi*8);
            u16x8 hb = *(const u16x8*)(h0 + (size_t)(base + lo)*64 + 32 + hi*8);
#pragma unroll
            for (int j = 0; j < 8; j++){
                af0[j] = (short)f2bf(fmaf(a0v[j],   bf2f(ha[j]), c0v[j]));
                af1[j] = (short)f2bf(fmaf(a0v[8+j], bf2f(hb[j]), c0v[8+j]));
            }
        }
        f32x4 acc[4];
#pragma unroll
        for (int nt = 0; nt < 4; nt++){
            acc[nt] = (f32x4){0.f, 0.f, 0.f, 0.f};
            acc[nt] = __builtin_amdgcn_mfma_f32_16x16x32_bf16(af0, bfr[0][nt], acc[nt], 0, 0, 0);
            acc[nt] = __builtin_amdgcn_mfma_f32_16x16x32_bf16(af1, bfr[1][nt], acc[nt], 0, 0, 0);
        }
#pragma unroll
        for (int nt = 0; nt < 4; nt++){
            float m = 0.f;
#pragma unroll
            for (int r = 0; r < 4; r++){
                bool valid = (hi*4 + r) < vc;     // D row = edge-in-group = 4*hi + r
                float h = valid ? fmaxf(acc[nt][r] + b1v[nt], 0.f) : 0.f;
                st1[nt] += h;
                st2[nt] = fmaf(h, h, st2[nt]);
                m = fmaxf(m, h);
            }
            m = fmaxf(m, __shfl_xor(m, 16));
            m = fmaxf(m, __shfl_xor(m, 32));
            if (lane < 16)
                atomicMax((unsigned int*)&nmax[(size_t)n*64 + nt*16 + lane], __float_as_uint(m));
        }
    }
    // BN1 stats: reduce rows across hi (xor 16,32), block LDS reduce, then atomics
#pragma unroll
    for (int nt = 0; nt < 4; nt++){
        st1[nt] += __shfl_xor(st1[nt], 16); st1[nt] += __shfl_xor(st1[nt], 32);
        st2[nt] += __shfl_xor(st2[nt], 16); st2[nt] += __shfl_xor(st2[nt], 32);
    }
    __shared__ float red[4*128];
    int w = threadIdx.x >> 6;
    if (lane < 16){
#pragma unroll
        for (int nt = 0; nt < 4; nt++){
            red[w*128 + nt*16 + lane]      = st1[nt];
            red[w*128 + 64 + nt*16 + lane] = st2[nt];
        }
    }
    __syncthreads();
    int t = threadIdx.x;
    if (t < 128){
        float v = red[t] + red[128 + t] + red[256 + t] + red[384 + t];
        if (t < 64) atomicAdd(&sum1[t], v);
        else        atomicAdd(&sq1[t - 64], v);
    }
}

// finalize: h = indeg>0 ? relu(a1*max + c1) : 0 ; reset nmax; fused mean-pool accumulation
__global__ __launch_bounds__(256) void k_fin(float* nmax, const int* __restrict__ deg,
        const float* __restrict__ a1, const float* __restrict__ c1,
        const int* __restrict__ batch, float* __restrict__ hout, float* pooll, int N, int B){
    int lane = threadIdx.x & 63;
    int wid = (blockIdx.x*256 + threadIdx.x) >> 6;
    int nw  = (gridDim.x*256) >> 6;
    int chunk = (N + nw - 1) / nw;
    int n0 = wid * chunk, n1 = min(n0 + chunk, N);
    float av = a1[lane], cv = c1[lane];
    int rep = wid & 7;
    float run = 0.f; int curb = -1;
    for (int n = n0; n < n1; n++){
        size_t idx = (size_t)n*64 + lane;
        float mv = nmax[idx];
        nmax[idx] = 0.f;
        float val = (deg[n] > 0) ? fmaxf(fmaf(av, mv, cv), 0.f) : 0.f;
        hout[idx] = val;
        int b = batch[n];
        if (b != curb){
            if (curb >= 0) atomicAdd(&pooll[(rep*B + curb)*64 + lane], run);
            run = 0.f; curb = b;
        }
        run += val;
    }
    if (curb >= 0) atomicAdd(&pooll[(rep*B + curb)*64 + lane], run);
}

// head: jump-cat pooled means -> lin1 -> relu -> lin2 -> log_softmax
__global__ __launch_bounds__(512) void k_head(const float* __restrict__ pool, const int* __restrict__ bstart,
        const float* __restrict__ l1W, const float* __restrict__ l1b,
        const float* __restrict__ l2W, const float* __restrict__ l2b,
        float* __restrict__ out, int B, int NCLS){
    __shared__ float js[8*256];
    __shared__ float z1[8*64];
    __shared__ float zs[8*40];
    int t = threadIdx.x;
    for (int i = t; i < B*256; i += 512){
        int b = i >> 8, k = i & 255;
        int l = k >> 6, c = k & 63;
        float s = 0.f;
        for (int r = 0; r < 8; r++) s += pool[((l*8 + r)*B + b)*64 + c];
        float cnt = (float)(bstart[b+1] - bstart[b]);
        js[b*256 + k] = s / fmaxf(cnt, 1.f);
    }
    __syncthreads();
    for (int i = t; i < B*64; i += 512){
        int b = i >> 6, c = i & 63;
        float acc = l1b[c];
        for (int k = 0; k < 256; k++) acc = fmaf(js[b*256 + k], l1W[k*64 + c], acc);
        z1[i] = fmaxf(acc, 0.f);
    }
    __syncthreads();
    for (int i = t; i < B*NCLS; i += 512){
        int b = i / NCLS, c = i - b*NCLS;
        float acc = l2b[c];
        for (int k = 0; k < 64; k++) acc = fmaf(z1[b*64 + k], l2W[k*NCLS + c], acc);
        zs[b*NCLS + c] = acc;
    }
    __syncthreads();
    if (t < B){
        float m = -1e30f;
        for (int c = 0; c < NCLS; c++) m = fmaxf(m, zs[t*NCLS + c]);
        float se = 0.f;
        for (int c = 0; c < NCLS; c++) se += expf(zs[t*NCLS + c] - m);
        float lse = m + logf(se);
        for (int c = 0; c < NCLS; c++) out[t*NCLS + c] = zs[t*NCLS + c] - lse;
    }
}

// ---------------- host ----------------

extern "C" void kernel_launch(void* const* d_in, const int* in_sizes, int n_in,
                              void* d_out, int out_size, void* d_ws, size_t ws_size,
                              hipStream_t stream){
    const float* x      = (const float*)d_in[0];
    const float* pos    = (const float*)d_in[1];
    const float* eattr  = (const float*)d_in[2];
    const int*   eidx   = (const int*)d_in[3];
    const int*   batch  = (const int*)d_in[4];
    const float* c1_W0  = (const float*)d_in[5];
    const float* c1_b0  = (const float*)d_in[6];
    const float* c1_g0  = (const float*)d_in[7];
    const float* c1_be0 = (const float*)d_in[8];
    const float* c1_W1  = (const float*)d_in[9];
    const float* c1_b1  = (const float*)d_in[10];
    const float* c1_g1  = (const float*)d_in[11];
    const float* c1_be1 = (const float*)d_in[12];
    const float* cw_W0  = (const float*)d_in[13];
    const float* cw_b0  = (const float*)d_in[14];
    const float* cw_g0  = (const float*)d_in[15];
    const float* cw_be0 = (const float*)d_in[16];
    const float* cw_W1  = (const float*)d_in[17];
    const float* cw_b1  = (const float*)d_in[18];
    const float* cw_g1  = (const float*)d_in[19];
    const float* cw_be1 = (const float*)d_in[20];
    const float* lin1_W = (const float*)d_in[21];
    const float* lin1_b = (const float*)d_in[22];
    const float* lin2_W = (const float*)d_in[23];
    const float* lin2_b = (const float*)d_in[24];
    float* out = (float*)d_out;

    int N = in_sizes[0] / 3;
    int E = in_sizes[2];
    int NCLS = in_sizes[24];
    int B = out_size / NCLS;
    const int* src = eidx;
    const int* dst = eidx + E;

    // workspace carve-up
    char* w = (char*)d_ws;
    auto alloc = [&](size_t bytes) -> char* {
        char* p = w;
        w += (bytes + 255) & ~(size_t)255;
        return p;
    };
    int Gmax = E/16 + N + 2;
    float* P        = (float*)alloc((size_t)N*64*4);
    float* Q        = (float*)alloc((size_t)N*64*4);
    float* hA       = (float*)alloc((size_t)N*64*4);
    float* hB       = (float*)alloc((size_t)N*64*4);
    float* nmax     = (float*)alloc((size_t)N*64*4);
    int*   deg      = (int*)alloc((size_t)N*4);
    int*   estart   = (int*)alloc((size_t)(N+1)*4);
    int*   gstart   = (int*)alloc((size_t)(N+1)*4);
    int*   cursor   = (int*)alloc((size_t)N*4);
    int*   src_c    = (int*)alloc((size_t)E*4);
    float* ea_c     = (float*)alloc((size_t)E*4);
    int*   grp_node = (int*)alloc((size_t)Gmax*4);
    int*   grp_base = (int*)alloc((size_t)Gmax*4);
    int*   grp_vc   = (int*)alloc((size_t)Gmax*4);
    int*   counters = (int*)alloc(256);
    int*   bstart   = (int*)alloc((size_t)(B+1)*4);
    float* stats    = (float*)alloc(4*256*4);   // per layer: sum0, sq0, sum1, sq1 (64 each)
    float* aff      = (float*)alloc(4*256*4);   // per layer: a0, c0, a1, c1
    unsigned short* w1bf = (unsigned short*)alloc(4*4096*2);
    float* pool     = (float*)alloc((size_t)4*8*B*64*4);

    size_t base_need = (size_t)(w - (char*)d_ws);
    size_t h0_need = (size_t)(E + 16)*64*2;
    bool useH0 = (ws_size >= base_need + h0_need + 4096);
    unsigned short* h0 = useH0 ? (unsigned short*)alloc(h0_need) : nullptr;

    float invE = 1.f / (float)E;
    int eblocks = (E + 255) / 256;
    int nblocks = (N + 255) / 256;

    k_init<<<2048, 256, 0, stream>>>(deg, cursor, N, stats, 4*256, pool, 4*8*B*64, nmax);
    k_hist<<<eblocks, 256, 0, stream>>>(dst, E, deg);
    k_scan<<<1, 1024, 0, stream>>>(deg, N, estart, gstart, counters);
    k_grpfill<<<nblocks, 256, 0, stream>>>(deg, estart, gstart, N, grp_node, grp_base, grp_vc);
    k_scatter<<<eblocks, 256, 0, stream>>>(src, dst, eattr, E, estart, cursor, src_c, ea_c);
    k_bounds<<<nblocks, 256, 0, stream>>>(batch, N, B, bstart);
    k_w1bf<<<64, 256, 0, stream>>>(c1_W1, cw_W1, w1bf);

    for (int l = 0; l < 4; l++){
        const float* feat = (l == 0) ? x : ((l == 1) ? hA : ((l == 2) ? hB : hA));
        float* hout = (l & 1) ? hB : hA;
        int F  = (l == 0) ? 3 : 64;
        int ra = (l == 0) ? 1 : 0;
        int rb = (l == 0) ? 7 : 67;
        const float* W0  = (l == 0) ? c1_W0  : cw_W0  + (size_t)(l-1)*134*64;
        const float* b0  = (l == 0) ? c1_b0  : cw_b0  + (l-1)*64;
        const float* g0  = (l == 0) ? c1_g0  : cw_g0  + (l-1)*64;
        const float* be0 = (l == 0) ? c1_be0 : cw_be0 + (l-1)*64;
        const float* b1  = (l == 0) ? c1_b1  : cw_b1  + (l-1)*64;
        const float* g1  = (l == 0) ? c1_g1  : cw_g1  + (l-1)*64;
        const float* be1 = (l == 0) ? c1_be1 : cw_be1 + (l-1)*64;
        const float* w0e = (l == 0) ? c1_W0 : nullptr;   // W0 row 0 = edge_attr weights
        const float* eaA = (l == 0) ? eattr : nullptr;
        (void)eaA;
        float* sum0 = stats + l*256;       float* sq0 = sum0 + 64;
        float* sum1 = sum0 + 128;          float* sq1 = sum0 + 192;
        float* a0 = aff + l*256;           float* c0 = a0 + 64;
        float* a1 = a0 + 128;              float* c1v = a0 + 192;
        const unsigned short* w1l = w1bf + (size_t)l*4096;
        float* pooll = pool + (size_t)l*8*B*64;

        k_nodeproj<<<512, 256, 0, stream>>>(pos, feat, F, W0, ra, rb, b0, P, Q, N);
        k_statsA<<<1280, 256, 0, stream>>>(P, Q, src_c, ea_c, w0e, grp_node, grp_base, grp_vc,
                                           counters, h0, sum0, sq0);
        k_bnfin<<<1, 64, 0, stream>>>(sum0, sq0, invE, g0, be0, a0, c0);
        if (useH0)
            k_passB2<false><<<1280, 256, 0, stream>>>(h0, P, Q, src_c, ea_c, w0e,
                                                      grp_node, grp_base, grp_vc, counters,
                                                      a0, c0, w1l, b1, nmax, sum1, sq1);
        else
            k_passB2<true><<<1280, 256, 0, stream>>>(h0, P, Q, src_c, ea_c, w0e,
                                                     grp_node, grp_base, grp_vc, counters,
                                                     a0, c0, w1l, b1, nmax, sum1, sq1);
        k_bnfin<<<1, 64, 0, stream>>>(sum1, sq1, invE, g1, be1, a1, c1v);
        k_fin<<<256, 256, 0, stream>>>(nmax, deg, a1, c1v, batch, hout, pooll, N, B);
    }

    k_head<<<1, 512, 0, stream>>>(pool, bstart, lin1_W, lin1_b, lin2_W, lin2_b, out, B, NCLS);
}

// Round 3
// 885.259 us; speedup vs baseline: 1.9489x; 1.2414x over previous
//
#include <hip/hip_runtime.h>

#define EPSV 1e-5f

typedef __attribute__((ext_vector_type(8))) short bf16x8;
typedef __attribute__((ext_vector_type(8))) unsigned short u16x8;
typedef __attribute__((ext_vector_type(4))) float f32x4;

__device__ inline unsigned short f2bf(float f){
    unsigned u = __float_as_uint(f);
    u += 0x7fffu + ((u >> 16) & 1u);
    return (unsigned short)(u >> 16);
}
__device__ inline float bf2f(unsigned short v){
    return __uint_as_float(((unsigned)v) << 16);
}

// ---------------- setup kernels ----------------

__global__ void k_init(int* deg, int* cursor, int N, int* counters,
                       float* stats, int statsN, float* pool, int poolN, float* nmax){
    int total = N * 64;
    for (int i = blockIdx.x*blockDim.x + threadIdx.x; i < total; i += gridDim.x*blockDim.x){
        nmax[i] = 0.f;
        if (i < N){ deg[i] = 0; cursor[i] = 0; }
        if (i < 8) counters[i] = 0;
        if (i < statsN) stats[i] = 0.f;
        if (i < poolN)  pool[i]  = 0.f;
    }
}

__global__ void k_hist(const int* dst, int E, int* deg){
    for (int e = blockIdx.x*blockDim.x + threadIdx.x; e < E; e += gridDim.x*blockDim.x)
        atomicAdd(&deg[dst[e]], 1);
}

// atomic bump-allocation of per-node edge/group base offsets (order arbitrary).
// counters[0]=edge cursor, counters[1]=group cursor (= total groups after).
__global__ __launch_bounds__(256) void k_alloc(const int* __restrict__ deg, int N,
        int* __restrict__ estart, int* __restrict__ gstart, int* counters){
    int lane = threadIdx.x & 63;
    for (int n = blockIdx.x*blockDim.x + threadIdx.x; n - lane < N; n += gridDim.x*blockDim.x){
        int d = (n < N) ? deg[n] : 0;
        int g = (d + 15) >> 4;
        int se = d, sg = g;
        for (int off = 1; off < 64; off <<= 1){
            int te = __shfl_up(se, off);
            int tg = __shfl_up(sg, off);
            if (lane >= off){ se += te; sg += tg; }
        }
        int be = 0, bg = 0;
        if (lane == 63){
            be = atomicAdd(&counters[0], se);
            bg = atomicAdd(&counters[1], sg);
        }
        be = __shfl(be, 63);
        bg = __shfl(bg, 63);
        if (n < N){
            estart[n] = be + se - d;
            gstart[n] = bg + sg - g;
        }
    }
}

__global__ void k_grpfill(const int* deg, const int* estart, const int* gstart, int N,
                          int* grp_node, int* grp_base, int* grp_vc){
    for (int n = blockIdx.x*blockDim.x + threadIdx.x; n < N; n += gridDim.x*blockDim.x){
        int dg = deg[n];
        int g0 = gstart[n];
        int e0 = estart[n];
        int ng = (dg + 15) >> 4;
        for (int j = 0; j < ng; j++){
            grp_node[g0 + j] = n;
            grp_base[g0 + j] = e0 + j*16;
            grp_vc[g0 + j] = min(dg - j*16, 16);
        }
    }
}

__global__ void k_scatter(const int* src, const int* dst, const float* ea, int E,
                          const int* estart, int* cursor, int* src_c, float* ea_c){
    for (int e = blockIdx.x*blockDim.x + threadIdx.x; e < E; e += gridDim.x*blockDim.x){
        int d = dst[e];
        int p = estart[d] + atomicAdd(&cursor[d], 1);
        src_c[p] = src[e];
        ea_c[p] = ea[e];
    }
}

__global__ void k_bounds(const int* batch, int N, int B, int* bstart){
    for (int n = blockIdx.x*blockDim.x + threadIdx.x; n < N; n += gridDim.x*blockDim.x){
        if (n == 0){ int b0 = batch[0]; for (int bb = 0; bb <= b0; bb++) bstart[bb] = 0; }
        int b1 = batch[n];
        int b2 = (n + 1 < N) ? batch[n + 1] : B;
        for (int bb = b1 + 1; bb <= b2; bb++) bstart[bb] = n + 1;
    }
}

__global__ void k_w1bf(const float* c1W1, const float* cwW1, unsigned short* w1bf){
    int i = blockIdx.x*blockDim.x + threadIdx.x;
    if (i < 4*4096){
        int l = i >> 12, r = i & 4095;
        float v = (l == 0) ? c1W1[r] : cwW1[(l-1)*4096 + r];
        w1bf[i] = f2bf(v);
    }
}

// ---------------- per-layer kernels ----------------

// P = xc @ Wa ; Q = xc @ (Wb - Wa) + b0   (xc = [pos(3), feat(F)]) — layer-0 only
__global__ __launch_bounds__(256) void k_nodeproj(const float* __restrict__ pos,
        const float* __restrict__ feat, int F, const float* __restrict__ W,
        int ra, int rb, const float* __restrict__ b0,
        float* __restrict__ P, float* __restrict__ Q, int N){
    __shared__ float sWa[67*64];
    __shared__ float sWd[67*64];
    int D = 3 + F;
    for (int i = threadIdx.x; i < D*64; i += 256){
        int k = i >> 6, c = i & 63;
        float wa = W[(ra + k)*64 + c];
        sWa[i] = wa;
        sWd[i] = W[(rb + k)*64 + c] - wa;
    }
    __syncthreads();
    int lane = threadIdx.x & 63;
    int wid = (blockIdx.x*256 + threadIdx.x) >> 6;
    int nw  = (gridDim.x*256) >> 6;
    float bb = b0[lane];
    for (int n = wid; n < N; n += nw){
        float p = 0.f, q = 0.f;
        for (int k = 0; k < 3; k++){
            float v = pos[n*3 + k];
            p = fmaf(v, sWa[k*64 + lane], p);
            q = fmaf(v, sWd[k*64 + lane], q);
        }
        for (int k = 0; k < F; k++){
            float v = feat[n*F + k];
            p = fmaf(v, sWa[(3+k)*64 + lane], p);
            q = fmaf(v, sWd[(3+k)*64 + lane], q);
        }
        P[(size_t)n*64 + lane] = p;
        Q[(size_t)n*64 + lane] = q + bb;
    }
}

// stats pass over sorted 16-edge groups: h = relu(P[src]+Q[dst](+ea*w0)),
// accumulate BN0 sum/sumsq, optionally store h as bf16 (compact layout).
__global__ __launch_bounds__(256) void k_statsA(const float* __restrict__ P, const float* __restrict__ Q,
        const int* __restrict__ src_c, const float* __restrict__ ea_c, const float* __restrict__ w0e,
        const int* __restrict__ grp_node, const int* __restrict__ grp_base, const int* __restrict__ grp_vc,
        const int* __restrict__ counters, unsigned short* __restrict__ h0,
        float* sum0, float* sq0){
    int lane = threadIdx.x & 63;
    int lo = lane & 15, hi = lane >> 4;
    int wid = (blockIdx.x*256 + threadIdx.x) >> 6;
    int nw  = (gridDim.x*256) >> 6;
    float w0v[16];
#pragma unroll
    for (int j = 0; j < 8; j++){
        w0v[j]   = w0e ? w0e[hi*8 + j]      : 0.f;
        w0v[8+j] = w0e ? w0e[32 + hi*8 + j] : 0.f;
    }
    float st1[16], st2[16];
#pragma unroll
    for (int j = 0; j < 16; j++){ st1[j] = 0.f; st2[j] = 0.f; }

    int NG = counters[1];
    for (int g = wid; g < NG; g += nw){
        int n = grp_node[g], base = grp_base[g], vc = grp_vc[g];
        bool val = lo < vc;
        int e = base + (val ? lo : 0);
        int s = src_c[e];
        float eav = (w0e && val) ? ea_c[e] : 0.f;
        const f32x4* P4 = (const f32x4*)(P + (size_t)s*64);
        const f32x4* Q4 = (const f32x4*)(Q + (size_t)n*64);
        f32x4 p0 = P4[2*hi], p1 = P4[2*hi+1], p2 = P4[2*hi+8], p3 = P4[2*hi+9];
        f32x4 q0 = Q4[2*hi], q1 = Q4[2*hi+1], q2 = Q4[2*hi+8], q3 = Q4[2*hi+9];
        u16x8 ha, hb;
#pragma unroll
        for (int j = 0; j < 8; j++){
            float pv = (j < 4) ? p0[j] : p1[j-4];
            float qv = (j < 4) ? q0[j] : q1[j-4];
            float h = fmaxf(fmaf(eav, w0v[j], pv + qv), 0.f);
            if (!val) h = 0.f;
            st1[j] += h; st2[j] = fmaf(h, h, st2[j]);
            ha[j] = f2bf(h);
        }
#pragma unroll
        for (int j = 0; j < 8; j++){
            float pv = (j < 4) ? p2[j] : p3[j-4];
            float qv = (j < 4) ? q2[j] : q3[j-4];
            float h = fmaxf(fmaf(eav, w0v[8+j], pv + qv), 0.f);
            if (!val) h = 0.f;
            st1[8+j] += h; st2[8+j] = fmaf(h, h, st2[8+j]);
            hb[j] = f2bf(h);
        }
        if (h0 && val){
            *(u16x8*)(h0 + (size_t)(base + lo)*64 + hi*8) = ha;
            *(u16x8*)(h0 + (size_t)(base + lo)*64 + 32 + hi*8) = hb;
        }
    }
    // reduce across the 16 lo-lanes (xor 1,2,4,8), then block LDS reduce, then atomics
#pragma unroll
    for (int m = 1; m < 16; m <<= 1){
#pragma unroll
        for (int j = 0; j < 16; j++){
            st1[j] += __shfl_xor(st1[j], m);
            st2[j] += __shfl_xor(st2[j], m);
        }
    }
    __shared__ float red[4*128];
    int w = threadIdx.x >> 6;
    if (lo == 0){
#pragma unroll
        for (int j = 0; j < 8; j++){
            red[w*128 + hi*8 + j]        = st1[j];
            red[w*128 + 32 + hi*8 + j]   = st1[8+j];
            red[w*128 + 64 + hi*8 + j]   = st2[j];
            red[w*128 + 96 + hi*8 + j]   = st2[8+j];
        }
    }
    __syncthreads();
    int t = threadIdx.x;
    if (t < 128){
        float v = red[t] + red[128 + t] + red[256 + t] + red[384 + t];
        if (t < 64) atomicAdd(&sum0[t], v);
        else        atomicAdd(&sq0[t - 64], v);
    }
}

// pass B: per 16-edge (single-dst) group: y = a0*h + c0 (BN0 finalize fused; h from
// h0 or recomputed), h1 = relu(y@W1+b1) via MFMA, scatter-max into nmax, BN1 stats.
template<bool REC>
__global__ __launch_bounds__(256) void k_passB2(const unsigned short* __restrict__ h0,
        const float* __restrict__ P, const float* __restrict__ Q,
        const int* __restrict__ src_c, const float* __restrict__ ea_c, const float* __restrict__ w0e,
        const int* __restrict__ grp_node, const int* __restrict__ grp_base, const int* __restrict__ grp_vc,
        const int* __restrict__ counters,
        const float* __restrict__ sum0, const float* __restrict__ sq0, float invE,
        const float* __restrict__ g0, const float* __restrict__ be0,
        const unsigned short* __restrict__ w1bf, const float* __restrict__ b1,
        float* nmax, float* sum1, float* sq1){
    int lane = threadIdx.x & 63;
    int lo = lane & 15, hi = lane >> 4;
    int wid = (blockIdx.x*256 + threadIdx.x) >> 6;
    int nw  = (gridDim.x*256) >> 6;

    // B fragments of W1 (bf16): B[k][n], n = 16*nt + lo, k = ks*32 + hi*8 + j
    bf16x8 bfr[2][4];
#pragma unroll
    for (int ks = 0; ks < 2; ks++)
#pragma unroll
        for (int nt = 0; nt < 4; nt++)
#pragma unroll
            for (int j = 0; j < 8; j++){
                int k = ks*32 + hi*8 + j;
                bfr[ks][nt][j] = (short)w1bf[k*64 + nt*16 + lo];
            }
    float b1v[4];
#pragma unroll
    for (int nt = 0; nt < 4; nt++) b1v[nt] = b1[nt*16 + lo];
    float a0v[16], c0v[16], w0v[16];
#pragma unroll
    for (int j = 0; j < 8; j++){
        int ch = hi*8 + j, ch2 = 32 + ch;
        float m  = sum0[ch]*invE;
        float vv = fmaxf(sq0[ch]*invE - m*m, 0.f);
        float r  = rsqrtf(vv + EPSV);
        a0v[j] = g0[ch]*r;  c0v[j] = be0[ch] - m*a0v[j];
        float m2  = sum0[ch2]*invE;
        float vv2 = fmaxf(sq0[ch2]*invE - m2*m2, 0.f);
        float r2  = rsqrtf(vv2 + EPSV);
        a0v[8+j] = g0[ch2]*r2;  c0v[8+j] = be0[ch2] - m2*a0v[8+j];
        w0v[j]   = w0e ? w0e[ch]  : 0.f;
        w0v[8+j] = w0e ? w0e[ch2] : 0.f;
    }

    float st1[4] = {0.f,0.f,0.f,0.f}, st2[4] = {0.f,0.f,0.f,0.f};
    int NG = counters[1];
    for (int g = wid; g < NG; g += nw){
        int n = grp_node[g], base = grp_base[g], vc = grp_vc[g];
        bf16x8 af0, af1;
        if (REC){
            bool val = lo < vc;
            int e = base + (val ? lo : 0);
            int s = src_c[e];
            float eav = (w0e && val) ? ea_c[e] : 0.f;
            const f32x4* P4 = (const f32x4*)(P + (size_t)s*64);
            const f32x4* Q4 = (const f32x4*)(Q + (size_t)n*64);
            f32x4 p0 = P4[2*hi], p1 = P4[2*hi+1], p2 = P4[2*hi+8], p3 = P4[2*hi+9];
            f32x4 q0 = Q4[2*hi], q1 = Q4[2*hi+1], q2 = Q4[2*hi+8], q3 = Q4[2*hi+9];
#pragma unroll
            for (int j = 0; j < 8; j++){
                float pv = (j < 4) ? p0[j] : p1[j-4];
                float qv = (j < 4) ? q0[j] : q1[j-4];
                float h = fmaxf(fmaf(eav, w0v[j], pv + qv), 0.f);
                af0[j] = (short)f2bf(fmaf(a0v[j], h, c0v[j]));
            }
#pragma unroll
            for (int j = 0; j < 8; j++){
                float pv = (j < 4) ? p2[j] : p3[j-4];
                float qv = (j < 4) ? q2[j] : q3[j-4];
                float h = fmaxf(fmaf(eav, w0v[8+j], pv + qv), 0.f);
                af1[j] = (short)f2bf(fmaf(a0v[8+j], h, c0v[8+j]));
            }
        } else {
            u16x8 ha = *(const u16x8*)(h0 + (size_t)(base + lo)*64 + hi*8);
            u16x8 hb = *(const u16x8*)(h0 + (size_t)(base + lo)*64 + 32 + hi*8);
#pragma unroll
            for (int j = 0; j < 8; j++){
                af0[j] = (short)f2bf(fmaf(a0v[j],   bf2f(ha[j]), c0v[j]));
                af1[j] = (short)f2bf(fmaf(a0v[8+j], bf2f(hb[j]), c0v[8+j]));
            }
        }
        f32x4 acc[4];
#pragma unroll
        for (int nt = 0; nt < 4; nt++){
            acc[nt] = (f32x4){0.f, 0.f, 0.f, 0.f};
            acc[nt] = __builtin_amdgcn_mfma_f32_16x16x32_bf16(af0, bfr[0][nt], acc[nt], 0, 0, 0);
            acc[nt] = __builtin_amdgcn_mfma_f32_16x16x32_bf16(af1, bfr[1][nt], acc[nt], 0, 0, 0);
        }
#pragma unroll
        for (int nt = 0; nt < 4; nt++){
            float m = 0.f;
#pragma unroll
            for (int r = 0; r < 4; r++){
                bool valid = (hi*4 + r) < vc;     // D row = edge-in-group = 4*hi + r
                float h = valid ? fmaxf(acc[nt][r] + b1v[nt], 0.f) : 0.f;
                st1[nt] += h;
                st2[nt] = fmaf(h, h, st2[nt]);
                m = fmaxf(m, h);
            }
            m = fmaxf(m, __shfl_xor(m, 16));
            m = fmaxf(m, __shfl_xor(m, 32));
            if (lane < 16)
                atomicMax((unsigned int*)&nmax[(size_t)n*64 + nt*16 + lane], __float_as_uint(m));
        }
    }
    // BN1 stats: reduce rows across hi (xor 16,32), block LDS reduce, then atomics
#pragma unroll
    for (int nt = 0; nt < 4; nt++){
        st1[nt] += __shfl_xor(st1[nt], 16); st1[nt] += __shfl_xor(st1[nt], 32);
        st2[nt] += __shfl_xor(st2[nt], 16); st2[nt] += __shfl_xor(st2[nt], 32);
    }
    __shared__ float red[4*128];
    int w = threadIdx.x >> 6;
    if (lane < 16){
#pragma unroll
        for (int nt = 0; nt < 4; nt++){
            red[w*128 + nt*16 + lane]      = st1[nt];
            red[w*128 + 64 + nt*16 + lane] = st2[nt];
        }
    }
    __syncthreads();
    int t = threadIdx.x;
    if (t < 128){
        float v = red[t] + red[128 + t] + red[256 + t] + red[384 + t];
        if (t < 64) atomicAdd(&sum1[t], v);
        else        atomicAdd(&sq1[t - 64], v);
    }
}

// finalize layer l (BN1-affine of scatter-max, fused a1/c1 computation, mean-pool
// accumulation, nmax reset) + optionally project P/Q for layer l+1 (cw weights).
template<bool PROJ>
__global__ __launch_bounds__(256) void k_finproj(float* nmax, const int* __restrict__ deg,
        const float* __restrict__ sum1, const float* __restrict__ sq1, float invE,
        const float* __restrict__ g1, const float* __restrict__ be1,
        const int* __restrict__ batch,
        const float* __restrict__ pos, const float* __restrict__ W, const float* __restrict__ b0n,
        float* __restrict__ P, float* __restrict__ Q, float* pooll, int N, int B){
    __shared__ float sWa[67*64];
    __shared__ float sWd[67*64];
    if (PROJ){
        for (int i = threadIdx.x; i < 67*64; i += 256){
            int k = i >> 6, c = i & 63;
            float wa = W[k*64 + c];
            sWa[i] = wa;
            sWd[i] = W[(67 + k)*64 + c] - wa;
        }
        __syncthreads();
    }
    int lane = threadIdx.x & 63;
    float m1 = sum1[lane]*invE;
    float v1 = fmaxf(sq1[lane]*invE - m1*m1, 0.f);
    float r1 = rsqrtf(v1 + EPSV);
    float av = g1[lane]*r1;
    float cv = be1[lane] - m1*av;
    float bb = PROJ ? b0n[lane] : 0.f;
    int wid = (blockIdx.x*256 + threadIdx.x) >> 6;
    int nw  = (gridDim.x*256) >> 6;
    int chunk = (N + nw - 1) / nw;
    int n0 = wid * chunk, n1 = min(n0 + chunk, N);
    int rep = wid & 7;
    float run = 0.f; int curb = -1;
    for (int n = n0; n < n1; n++){
        size_t idx = (size_t)n*64 + lane;
        float mv = nmax[idx];
        nmax[idx] = 0.f;
        float val = (deg[n] > 0) ? fmaxf(fmaf(av, mv, cv), 0.f) : 0.f;
        int b = batch[n];
        if (b != curb){
            if (curb >= 0) atomicAdd(&pooll[(rep*B + curb)*64 + lane], run);
            run = 0.f; curb = b;
        }
        run += val;
        if (PROJ){
            float p = 0.f, q = 0.f;
            for (int k = 0; k < 3; k++){
                float v = pos[n*3 + k];
                p = fmaf(v, sWa[k*64 + lane], p);
                q = fmaf(v, sWd[k*64 + lane], q);
            }
#pragma unroll
            for (int k = 0; k < 64; k++){
                float v = __shfl(val, k);
                p = fmaf(v, sWa[(3+k)*64 + lane], p);
                q = fmaf(v, sWd[(3+k)*64 + lane], q);
            }
            P[idx] = p;
            Q[idx] = q + bb;
        }
    }
    if (curb >= 0) atomicAdd(&pooll[(rep*B + curb)*64 + lane], run);
}

// head: jump-cat pooled means -> lin1 -> relu -> lin2 -> log_softmax
__global__ __launch_bounds__(512) void k_head(const float* __restrict__ pool, const int* __restrict__ bstart,
        const float* __restrict__ l1W, const float* __restrict__ l1b,
        const float* __restrict__ l2W, const float* __restrict__ l2b,
        float* __restrict__ out, int B, int NCLS){
    __shared__ float js[8*256];
    __shared__ float z1[8*64];
    __shared__ float zs[8*40];
    int t = threadIdx.x;
    for (int i = t; i < B*256; i += 512){
        int b = i >> 8, k = i & 255;
        int l = k >> 6, c = k & 63;
        float s = 0.f;
        for (int r = 0; r < 8; r++) s += pool[((l*8 + r)*B + b)*64 + c];
        float cnt = (float)(bstart[b+1] - bstart[b]);
        js[b*256 + k] = s / fmaxf(cnt, 1.f);
    }
    __syncthreads();
    for (int i = t; i < B*64; i += 512){
        int b = i >> 6, c = i & 63;
        float acc = l1b[c];
        for (int k = 0; k < 256; k++) acc = fmaf(js[b*256 + k], l1W[k*64 + c], acc);
        z1[i] = fmaxf(acc, 0.f);
    }
    __syncthreads();
    for (int i = t; i < B*NCLS; i += 512){
        int b = i / NCLS, c = i - b*NCLS;
        float acc = l2b[c];
        for (int k = 0; k < 64; k++) acc = fmaf(z1[b*64 + k], l2W[k*NCLS + c], acc);
        zs[b*NCLS + c] = acc;
    }
    __syncthreads();
    if (t < B){
        float m = -1e30f;
        for (int c = 0; c < NCLS; c++) m = fmaxf(m, zs[t*NCLS + c]);
        float se = 0.f;
        for (int c = 0; c < NCLS; c++) se += expf(zs[t*NCLS + c] - m);
        float lse = m + logf(se);
        for (int c = 0; c < NCLS; c++) out[t*NCLS + c] = zs[t*NCLS + c] - lse;
    }
}

// ---------------- host ----------------

extern "C" void kernel_launch(void* const* d_in, const int* in_sizes, int n_in,
                              void* d_out, int out_size, void* d_ws, size_t ws_size,
                              hipStream_t stream){
    const float* x      = (const float*)d_in[0];
    const float* pos    = (const float*)d_in[1];
    const float* eattr  = (const float*)d_in[2];
    const int*   eidx   = (const int*)d_in[3];
    const int*   batch  = (const int*)d_in[4];
    const float* c1_W0  = (const float*)d_in[5];
    const float* c1_b0  = (const float*)d_in[6];
    const float* c1_g0  = (const float*)d_in[7];
    const float* c1_be0 = (const float*)d_in[8];
    const float* c1_W1  = (const float*)d_in[9];
    const float* c1_b1  = (const float*)d_in[10];
    const float* c1_g1  = (const float*)d_in[11];
    const float* c1_be1 = (const float*)d_in[12];
    const float* cw_W0  = (const float*)d_in[13];
    const float* cw_b0  = (const float*)d_in[14];
    const float* cw_g0  = (const float*)d_in[15];
    const float* cw_be0 = (const float*)d_in[16];
    const float* cw_W1  = (const float*)d_in[17];
    const float* cw_b1  = (const float*)d_in[18];
    const float* cw_g1  = (const float*)d_in[19];
    const float* cw_be1 = (const float*)d_in[20];
    const float* lin1_W = (const float*)d_in[21];
    const float* lin1_b = (const float*)d_in[22];
    const float* lin2_W = (const float*)d_in[23];
    const float* lin2_b = (const float*)d_in[24];
    float* out = (float*)d_out;

    int N = in_sizes[0] / 3;
    int E = in_sizes[2];
    int NCLS = in_sizes[24];
    int B = out_size / NCLS;
    const int* src = eidx;
    const int* dst = eidx + E;

    // workspace carve-up
    char* w = (char*)d_ws;
    auto alloc = [&](size_t bytes) -> char* {
        char* p = w;
        w += (bytes + 255) & ~(size_t)255;
        return p;
    };
    int Gmax = E/16 + N + 2;
    float* P        = (float*)alloc((size_t)N*64*4);
    float* Q        = (float*)alloc((size_t)N*64*4);
    float* nmax     = (float*)alloc((size_t)N*64*4);
    int*   deg      = (int*)alloc((size_t)N*4);
    int*   estart   = (int*)alloc((size_t)(N+1)*4);
    int*   gstart   = (int*)alloc((size_t)(N+1)*4);
    int*   cursor   = (int*)alloc((size_t)N*4);
    int*   src_c    = (int*)alloc((size_t)E*4);
    float* ea_c     = (float*)alloc((size_t)E*4);
    int*   grp_node = (int*)alloc((size_t)Gmax*4);
    int*   grp_base = (int*)alloc((size_t)Gmax*4);
    int*   grp_vc   = (int*)alloc((size_t)Gmax*4);
    int*   counters = (int*)alloc(256);
    int*   bstart   = (int*)alloc((size_t)(B+1)*4);
    float* stats    = (float*)alloc(4*256*4);   // per layer: sum0, sq0, sum1, sq1 (64 each)
    unsigned short* w1bf = (unsigned short*)alloc(4*4096*2);
    float* pool     = (float*)alloc((size_t)4*8*B*64*4);

    size_t base_need = (size_t)(w - (char*)d_ws);
    size_t h0_need = (size_t)(E + 16)*64*2;
    bool useH0 = (ws_size >= base_need + h0_need + 4096);
    unsigned short* h0 = useH0 ? (unsigned short*)alloc(h0_need) : nullptr;

    float invE = 1.f / (float)E;
    int eblocks = (E + 255) / 256;
    int nblocks = (N + 255) / 256;

    k_init<<<2048, 256, 0, stream>>>(deg, cursor, N, counters, stats, 4*256, pool, 4*8*B*64, nmax);
    k_hist<<<eblocks, 256, 0, stream>>>(dst, E, deg);
    k_alloc<<<nblocks, 256, 0, stream>>>(deg, N, estart, gstart, counters);
    k_grpfill<<<nblocks, 256, 0, stream>>>(deg, estart, gstart, N, grp_node, grp_base, grp_vc);
    k_scatter<<<eblocks, 256, 0, stream>>>(src, dst, eattr, E, estart, cursor, src_c, ea_c);
    k_bounds<<<nblocks, 256, 0, stream>>>(batch, N, B, bstart);
    k_w1bf<<<64, 256, 0, stream>>>(c1_W1, cw_W1, w1bf);

    // layer-0 projection from x
    k_nodeproj<<<512, 256, 0, stream>>>(pos, x, 3, c1_W0, 1, 7, c1_b0, P, Q, N);

    for (int l = 0; l < 4; l++){
        const float* g0  = (l == 0) ? c1_g0  : cw_g0  + (l-1)*64;
        const float* be0 = (l == 0) ? c1_be0 : cw_be0 + (l-1)*64;
        const float* b1  = (l == 0) ? c1_b1  : cw_b1  + (l-1)*64;
        const float* g1  = (l == 0) ? c1_g1  : cw_g1  + (l-1)*64;
        const float* be1 = (l == 0) ? c1_be1 : cw_be1 + (l-1)*64;
        const float* w0e = (l == 0) ? c1_W0 : nullptr;   // W0 row 0 = edge_attr weights
        float* sum0 = stats + l*256;       float* sq0 = sum0 + 64;
        float* sum1 = sum0 + 128;          float* sq1 = sum0 + 192;
        const unsigned short* w1l = w1bf + (size_t)l*4096;
        float* pooll = pool + (size_t)l*8*B*64;

        k_statsA<<<1280, 256, 0, stream>>>(P, Q, src_c, ea_c, w0e, grp_node, grp_base, grp_vc,
                                           counters, h0, sum0, sq0);
        if (useH0)
            k_passB2<false><<<1280, 256, 0, stream>>>(h0, P, Q, src_c, ea_c, w0e,
                                                      grp_node, grp_base, grp_vc, counters,
                                                      sum0, sq0, invE, g0, be0, w1l, b1, nmax, sum1, sq1);
        else
            k_passB2<true><<<1280, 256, 0, stream>>>(h0, P, Q, src_c, ea_c, w0e,
                                                     grp_node, grp_base, grp_vc, counters,
                                                     sum0, sq0, invE, g0, be0, w1l, b1, nmax, sum1, sq1);
        if (l < 3)
            k_finproj<true><<<512, 256, 0, stream>>>(nmax, deg, sum1, sq1, invE, g1, be1, batch,
                                                     pos, cw_W0 + (size_t)l*134*64, cw_b0 + l*64,
                                                     P, Q, pooll, N, B);
        else
            k_finproj<false><<<256, 256, 0, stream>>>(nmax, deg, sum1, sq1, invE, g1, be1, batch,
                                                      pos, nullptr, nullptr,
                                                      P, Q, pooll, N, B);
    }

    k_head<<<1, 512, 0, stream>>>(pool, bstart, lin1_W, lin1_b, lin2_W, lin2_b, out, B, NCLS);
}